// Round 6
// baseline (198.145 us; speedup 1.0000x reference)
//
#include <hip/hip_runtime.h>

// DropStripes: out = in * keep, keep(b,t) = !any_s( bgns[b,s] <= t < bgns[b,s]+dist[b,s] )
// Shapes: input (B=64, C=8, T=2048, F=128) fp32; distances (B,2) i32; bgns (B,2) i32.
// Pure streaming masked copy: 512 MiB in + 512 MiB out, memory-bound.
// Ladder: R1 grid-stride plain          = 200.0 us (5.37 TB/s)
//         R3 block-uniform +unroll4 +nt = 191.6 us (5.60 TB/s)  <- best
//         R4 R3 minus nt                = 204.7 us  -> nt worth +6.8%, keep
//         R5 R3 with BATCH=8            = 191.9 us  -> MLP depth neutral
// R6: grid 8192 -> 2048 blocks (8/CU, full occupancy, 4x work per block) --
//     kill per-block launch/retire churn (G11). Single variable vs R5.

typedef float f4 __attribute__((ext_vector_type(4)));

constexpr int Bn = 64;
constexpr int Cn = 8;
constexpr int Tn = 2048;    // power of two -> mask
constexpr int Fn = 128;     // 32 float4 per row
constexpr int STRIPES = 2;

constexpr int N4_PER_B     = Cn * Tn * (Fn / 4);      // 524288 f4 per batch
constexpr int BLOCKS_PER_B = 32;                      // b is block-uniform; 64*32 = 2048 blocks
constexpr int CHUNK        = N4_PER_B / BLOCKS_PER_B; // 16384 f4 per block
constexpr int BLOCK        = 256;
constexpr int ITERS        = CHUNK / BLOCK;           // 64, tail-free
constexpr int BATCH        = 8;                       // loads in flight per thread

__global__ __launch_bounds__(BLOCK) void
drop_stripes_kernel(const f4* __restrict__ in,
                    const int* __restrict__ distances,
                    const int* __restrict__ bgns,
                    f4* __restrict__ out)
{
    const int b     = blockIdx.x >> 5;                  // / BLOCKS_PER_B (uniform)
    const int chunk = blockIdx.x & (BLOCKS_PER_B - 1);
    const int base  = b * N4_PER_B + chunk * CHUNK;

    // Block-uniform -> scalar loads, once per block.
    const int s0 = bgns[b * STRIPES + 0];
    const int s1 = bgns[b * STRIPES + 1];
    const int d0 = distances[b * STRIPES + 0];
    const int d1 = distances[b * STRIPES + 1];

    #pragma unroll
    for (int i = 0; i < ITERS; i += BATCH) {
        int idx[BATCH];
        f4  v[BATCH];

        #pragma unroll
        for (int j = 0; j < BATCH; ++j) {
            idx[j] = base + (i + j) * BLOCK + threadIdx.x;
            v[j]   = __builtin_nontemporal_load(&in[idx[j]]);
        }

        #pragma unroll
        for (int j = 0; j < BATCH; ++j) {
            const int t = (idx[j] >> 5) & (Tn - 1);
            const bool keep = ((unsigned)(t - s0) >= (unsigned)d0) &
                              ((unsigned)(t - s1) >= (unsigned)d1);
            f4 r = keep ? v[j] : (f4)(0.f);
            __builtin_nontemporal_store(r, &out[idx[j]]);
        }
    }
}

extern "C" void kernel_launch(void* const* d_in, const int* in_sizes, int n_in,
                              void* d_out, int out_size, void* d_ws, size_t ws_size,
                              hipStream_t stream)
{
    const f4* in         = (const f4*)d_in[0];
    const int* distances = (const int*)d_in[1];
    const int* bgns      = (const int*)d_in[2];
    f4* out              = (f4*)d_out;

    const int grid = Bn * BLOCKS_PER_B;   // 2048 blocks = 8 per CU, tail-free

    drop_stripes_kernel<<<grid, BLOCK, 0, stream>>>(in, distances, bgns, out);
}

// Round 7
// 191.376 us; speedup vs baseline: 1.0354x; 1.0354x over previous
//
#include <hip/hip_runtime.h>

// DropStripes: out = in * keep, keep(b,t) = !any_s( bgns[b,s] <= t < bgns[b,s]+dist[b,s] )
// Shapes: input (B=64, C=8, T=2048, F=128) fp32; distances (B,2) i32; bgns (B,2) i32.
// Pure streaming masked copy: 512 MiB in + 512 MiB out, memory-bound.
// Ladder: R1 grid-stride plain          = 200.0 us (5.37 TB/s)
//         R3 block-uniform +unroll4 +nt = 191.6 us (5.60 TB/s)  <- best
//         R4 R3 minus nt                = 204.7 us  -> nt worth +6.8%, keep
//         R5 R3 with BATCH=8            = 191.9 us  -> MLP depth neutral
//         R6 grid 8192->2048            = 198.1 us  -> oversubscription wins, keep 8192
// R7: revert to R5 (best). 89% of measured copy ceiling; declaring roofline.

typedef float f4 __attribute__((ext_vector_type(4)));

constexpr int Bn = 64;
constexpr int Cn = 8;
constexpr int Tn = 2048;    // power of two -> mask
constexpr int Fn = 128;     // 32 float4 per row
constexpr int STRIPES = 2;

constexpr int N4_PER_B     = Cn * Tn * (Fn / 4);      // 524288 f4 per batch
constexpr int BLOCKS_PER_B = 128;                     // b is block-uniform; 64*128 = 8192 blocks
constexpr int CHUNK        = N4_PER_B / BLOCKS_PER_B; // 4096 f4 per block
constexpr int BLOCK        = 256;
constexpr int ITERS        = CHUNK / BLOCK;           // 16, tail-free
constexpr int BATCH        = 8;                       // loads in flight per thread

__global__ __launch_bounds__(BLOCK) void
drop_stripes_kernel(const f4* __restrict__ in,
                    const int* __restrict__ distances,
                    const int* __restrict__ bgns,
                    f4* __restrict__ out)
{
    const int b     = blockIdx.x >> 7;                  // / BLOCKS_PER_B (uniform)
    const int chunk = blockIdx.x & (BLOCKS_PER_B - 1);
    const int base  = b * N4_PER_B + chunk * CHUNK;

    // Block-uniform -> scalar loads, once per block.
    const int s0 = bgns[b * STRIPES + 0];
    const int s1 = bgns[b * STRIPES + 1];
    const int d0 = distances[b * STRIPES + 0];
    const int d1 = distances[b * STRIPES + 1];

    #pragma unroll
    for (int i = 0; i < ITERS; i += BATCH) {
        int idx[BATCH];
        f4  v[BATCH];

        #pragma unroll
        for (int j = 0; j < BATCH; ++j) {
            idx[j] = base + (i + j) * BLOCK + threadIdx.x;
            v[j]   = __builtin_nontemporal_load(&in[idx[j]]);
        }

        #pragma unroll
        for (int j = 0; j < BATCH; ++j) {
            const int t = (idx[j] >> 5) & (Tn - 1);
            const bool keep = ((unsigned)(t - s0) >= (unsigned)d0) &
                              ((unsigned)(t - s1) >= (unsigned)d1);
            f4 r = keep ? v[j] : (f4)(0.f);
            __builtin_nontemporal_store(r, &out[idx[j]]);
        }
    }
}

extern "C" void kernel_launch(void* const* d_in, const int* in_sizes, int n_in,
                              void* d_out, int out_size, void* d_ws, size_t ws_size,
                              hipStream_t stream)
{
    const f4* in         = (const f4*)d_in[0];
    const int* distances = (const int*)d_in[1];
    const int* bgns      = (const int*)d_in[2];
    f4* out              = (f4*)d_out;

    const int grid = Bn * BLOCKS_PER_B;   // 8192 blocks, tail-free

    drop_stripes_kernel<<<grid, BLOCK, 0, stream>>>(in, distances, bgns, out);
}